// Round 1
// 1393.880 us; speedup vs baseline: 1.1876x; 1.1876x over previous
//
#include <hip/hip_runtime.h>
#include <math.h>

// ---------------------------------------------------------------------------
// QuantMlp: out = fq(h)@fq(W2)^T + b2,  h = gelu(fq(LN(x))@fq(W1)^T + b1)
// fq: per-tensor symmetric int8 fake-quant. q-values are small integers ->
// EXACT in bf16; bf16-MFMA fp32 accumulation of q*q' is exact (sums < 2^24).
//
// R2 -> R3: GEMMs rewritten on the 256x256 / BK=64 / 8-wave 8-phase template
// (T1 XCD swizzle + T2 LDS chunk-XOR swizzle + T3/T4 counted-vmcnt phase
// pipeline + T5 setprio). Per buffer, 4 independently staged 16KB K-half
// regions {A.k0, A.k1, B.k0, B.k1}; region overwrite is always >=1 full
// barrier after its last read (schedule verified below). vmcnt(4) only at
// phases 4/8 of each 2-K-tile iteration; vmcnt(0) only at the tail.
// ---------------------------------------------------------------------------

typedef __attribute__((ext_vector_type(4))) float  f4;
typedef __attribute__((ext_vector_type(8))) __bf16 bf16x8;
typedef __attribute__((ext_vector_type(4))) unsigned short us4;
typedef __attribute__((ext_vector_type(4))) unsigned int   u4;

__device__ __forceinline__ unsigned short f2bf_rn(float f) {
    unsigned u = __float_as_uint(f);
    u += 0x7FFFu + ((u >> 16) & 1u);          // round-to-nearest-even
    return (unsigned short)(u >> 16);
}
__device__ __forceinline__ float bf2f(unsigned short b) {
    return __uint_as_float(((unsigned)b) << 16);
}

// all-threads block -> single device atomicMax of a non-negative float
template <int NW>
__device__ __forceinline__ void block_atomic_max(float v, unsigned* slot,
                                                 float* red, int tid) {
    int lane = tid & 63, wv = tid >> 6;
    #pragma unroll
    for (int m = 32; m; m >>= 1) v = fmaxf(v, __shfl_xor(v, m));
    if (lane == 0) red[wv] = v;
    __syncthreads();
    if (tid == 0) {
        float r = red[0];
        #pragma unroll
        for (int i = 1; i < NW; i++) r = fmaxf(r, red[i]);
        atomicMax(slot, __float_as_uint(r));
    }
}

// async 16B global->LDS (wave-uniform base + lane*16 by construction)
__device__ __forceinline__ void gll16(const void* g, void* l) {
    __builtin_amdgcn_global_load_lds(
        (const __attribute__((address_space(1))) void*)g,
        (__attribute__((address_space(3))) void*)l, 16, 0, 0);
}

// ---------------------------------------------------------------------------
// LayerNorm helpers: one wave per row of 768 (12 floats/lane as 3x float4)
// ---------------------------------------------------------------------------
__device__ __forceinline__ void ln_row(const f4* xr, int lane, f4 v[3],
                                       float& mu, float& rs) {
    float s = 0.f;
    #pragma unroll
    for (int c = 0; c < 3; c++) {
        v[c] = xr[lane + 64 * c];
        s += v[c][0] + v[c][1] + v[c][2] + v[c][3];
    }
    #pragma unroll
    for (int m = 1; m < 64; m <<= 1) s += __shfl_xor(s, m);
    mu = s * (1.0f / 768.0f);
    float q = 0.f;
    #pragma unroll
    for (int c = 0; c < 3; c++) {
        #pragma unroll
        for (int k = 0; k < 4; k++) { float d = v[c][k] - mu; q += d * d; }
    }
    #pragma unroll
    for (int m = 1; m < 64; m <<= 1) q += __shfl_xor(q, m);
    rs = rsqrtf(q * (1.0f / 768.0f) + 1e-5f);
}

__global__ __launch_bounds__(256) void ln_absmax_kernel(
        const float* __restrict__ x, const float* __restrict__ gamma,
        const float* __restrict__ beta, unsigned* __restrict__ slot, long NR) {
    __shared__ float red[4];
    int tid = threadIdx.x, lane = tid & 63, wv = tid >> 6;
    const f4* g4 = (const f4*)gamma;
    const f4* b4 = (const f4*)beta;
    long rstep = (long)gridDim.x * 4;
    float wmax = 0.f;
    for (long row = (long)blockIdx.x * 4 + wv; row < NR; row += rstep) {
        const f4* xr = (const f4*)(x + row * 768);
        f4 v[3]; float mu, rs;
        ln_row(xr, lane, v, mu, rs);
        #pragma unroll
        for (int c = 0; c < 3; c++) {
            f4 g = g4[lane + 64 * c], b = b4[lane + 64 * c];
            #pragma unroll
            for (int k = 0; k < 4; k++) {
                float xn = (v[c][k] - mu) * rs * g[k] + b[k];
                wmax = fmaxf(wmax, fabsf(xn));
            }
        }
    }
    block_atomic_max<4>(wmax, slot, red, tid);
}

__global__ __launch_bounds__(256) void ln_quant_kernel(
        const float* __restrict__ x, const float* __restrict__ gamma,
        const float* __restrict__ beta, unsigned short* __restrict__ qx,
        const unsigned* __restrict__ amax_bits, long NR) {
    int tid = threadIdx.x, lane = tid & 63, wv = tid >> 6;
    long row = (long)blockIdx.x * 4 + wv;
    if (row >= NR) return;
    float sx = fmaxf(__uint_as_float(*amax_bits) * (1.0f / 128.0f), 1e-12f);
    const f4* xr = (const f4*)(x + row * 768);
    const f4* g4 = (const f4*)gamma;
    const f4* b4 = (const f4*)beta;
    f4 v[3]; float mu, rs;
    ln_row(xr, lane, v, mu, rs);
    us4* qr = (us4*)(qx + row * 768);
    #pragma unroll
    for (int c = 0; c < 3; c++) {
        f4 g = g4[lane + 64 * c], b = b4[lane + 64 * c];
        us4 o;
        #pragma unroll
        for (int k = 0; k < 4; k++) {
            float xn = (v[c][k] - mu) * rs * g[k] + b[k];
            float q = fminf(fmaxf(rintf(xn / sx), -128.0f), 127.0f);
            o[k] = f2bf_rn(q);   // exact: small integer
        }
        qr[lane + 64 * c] = o;
    }
}

// ---------------------------------------------------------------------------
// Weight absmax + quantize (fp32 -> integer-valued bf16)
// ---------------------------------------------------------------------------
__global__ __launch_bounds__(256) void absmax_kernel(
        const float* __restrict__ w, long n4, unsigned* __restrict__ slot) {
    __shared__ float red[4];
    int tid = threadIdx.x;
    long stride = (long)gridDim.x * 256;
    float mx = 0.f;
    for (long i = (long)blockIdx.x * 256 + tid; i < n4; i += stride) {
        f4 v = ((const f4*)w)[i];
        mx = fmaxf(mx, fmaxf(fmaxf(fabsf(v[0]), fabsf(v[1])),
                             fmaxf(fabsf(v[2]), fabsf(v[3]))));
    }
    block_atomic_max<4>(mx, slot, red, tid);
}

__global__ __launch_bounds__(256) void quant_w_kernel(
        const float* __restrict__ w, unsigned short* __restrict__ qw, long n4,
        const unsigned* __restrict__ amax_bits) {
    long i = (long)blockIdx.x * 256 + threadIdx.x;
    if (i >= n4) return;
    float s = fmaxf(__uint_as_float(*amax_bits) * (1.0f / 127.0f), 1e-12f);
    f4 v = ((const f4*)w)[i];
    us4 o;
    #pragma unroll
    for (int k = 0; k < 4; k++) {
        float q = fminf(fmaxf(rintf(v[k] / s), -127.0f), 127.0f);
        o[k] = f2bf_rn(q);
    }
    ((us4*)qw)[i] = o;
}

// h (bf16) -> q (integer-valued bf16), in place. 8 elements / thread.
__global__ __launch_bounds__(256) void quant_h_kernel(
        unsigned short* __restrict__ h, const unsigned* __restrict__ amax_bits,
        long n8) {
    long i = (long)blockIdx.x * 256 + threadIdx.x;
    if (i >= n8) return;
    float s = fmaxf(__uint_as_float(*amax_bits) * (1.0f / 128.0f), 1e-12f);
    u4 d = ((const u4*)h)[i];
    u4 o;
    #pragma unroll
    for (int k = 0; k < 4; k++) {
        float a = bf2f((unsigned short)(d[k] & 0xFFFFu));
        float b = bf2f((unsigned short)(d[k] >> 16));
        float qa = fminf(fmaxf(rintf(a / s), -128.0f), 127.0f);
        float qb = fminf(fmaxf(rintf(b / s), -128.0f), 127.0f);
        o[k] = (unsigned)f2bf_rn(qa) | ((unsigned)f2bf_rn(qb) << 16);
    }
    ((u4*)h)[i] = o;
}

// ---------------------------------------------------------------------------
// GEMM: C[M,N] = A[M,K] * B[N,K]^T, A/B integer-valued bf16, K-contiguous.
// 256x256 tile, BK=64, 512 threads = 8 waves (2M x 4N), per-wave 128x64 out.
// LDS 128KB = 2 buffers x {A.k0, A.k1, B.k0, B.k1} 16KB regions.
//   region layout: 256 rows x 4 chunks of 16B; chunk swizzle c' = c^((r>>1)&3)
//   (pre-swizzled GLOBAL source, linear LDS dest, swizzled ds_read -> rule 21;
//    consecutive-8-lane bank-groups all distinct -> conflict-free b128 reads).
// Per K-tile: 4 phases {ds_read subtile | stage 1 half-tile | barrier |
// lgkmcnt(0) | setprio(1) 16 MFMA setprio(0) | [vmcnt(4) at ph3] | barrier}.
// Region overwrite schedule (iter t = tile t in buf[t&1]):
//   ph0:(t+1).A.k1  ph1:(t+1).B.k1  ph2:(t+2).A.k0  ph3:(t+2).B.k0
//   last reads of tile t: A.k0@ph1 B.k0@ph0 A.k1@ph3 B.k1@ph2 -> every
//   overwrite issue is >=1 closing barrier after the region's last read.
// vmcnt(4) at ph3/ph7 leaves exactly the next-next tile's k0 halves in
// flight; everything the next tile reads is drained.  NT=K/64 even, >=4.
// ---------------------------------------------------------------------------
#define AB(b,kh) ((b)*65536 + (kh)*16384)
#define BB(b,kh) ((b)*65536 + 32768 + (kh)*16384)
#define STA(p, eo, rb) gll16(gA[p] + (eo), lds + (rb) + ldst[p])
#define STB(p, eo, rb) gll16(gB[p] + (eo), lds + (rb) + ldst[p])
#define VMC(n) asm volatile("s_waitcnt vmcnt(" #n ")" ::: "memory")

#define PHASE(BUF, KS, MB, STAGE, TAIL) do {                                  \
    bf16x8 aF[4];                                                             \
    _Pragma("unroll")                                                         \
    for (int m_ = 0; m_ < 4; m_++)                                            \
      aF[m_] = *(const bf16x8*)(lds + AB(BUF,KS) + aoff + (MB + m_) * 1024);  \
    if (MB == 0) {                                                            \
      _Pragma("unroll")                                                       \
      for (int n_ = 0; n_ < 4; n_++)                                          \
        bF[n_] = *(const bf16x8*)(lds + BB(BUF,KS) + boff + n_ * 1024);       \
    }                                                                         \
    STAGE                                                                     \
    __builtin_amdgcn_s_barrier();                                             \
    asm volatile("s_waitcnt lgkmcnt(0)" ::: "memory");                        \
    __builtin_amdgcn_s_setprio(1);                                            \
    _Pragma("unroll")                                                         \
    for (int m_ = 0; m_ < 4; m_++)                                            \
      _Pragma("unroll")                                                       \
      for (int n_ = 0; n_ < 4; n_++)                                          \
        acc[MB + m_][n_] = __builtin_amdgcn_mfma_f32_16x16x32_bf16(           \
            aF[m_], bF[n_], acc[MB + m_][n_], 0, 0, 0);                       \
    __builtin_amdgcn_s_setprio(0);                                            \
    TAIL                                                                      \
    __builtin_amdgcn_s_barrier();                                             \
  } while (0)

template <int EPI>
__global__ __launch_bounds__(512, 2) void gemm256(
        const unsigned short* __restrict__ A, const unsigned short* __restrict__ B,
        int K, const unsigned* __restrict__ amaxA_bits,
        const unsigned* __restrict__ amaxB_bits, const float* __restrict__ bias,
        void* __restrict__ Cout, int ldc, unsigned* __restrict__ amax_out) {
    __shared__ __align__(16) char lds[131072];
    __shared__ float red[8];
    int tid = threadIdx.x, lane = tid & 63, wv = tid >> 6;
    int wm = wv >> 2, wn = wv & 3;

    // T1: XCD-contiguous block remap (nwg % 8 == 0 for both launches)
    int nwg = gridDim.x * gridDim.y;
    int flat = blockIdx.y * gridDim.x + blockIdx.x;
    int swz = (flat & 7) * (nwg >> 3) + (flat >> 3);
    int ncol = gridDim.x;
    long rowBase = (long)(swz / ncol) * 256;
    long colBase = (long)(swz % ncol) * 256;

    f4 acc[8][4] = {};
    bf16x8 bF[4];

    // read-side per-thread offsets: frag row = Rbase + (lane&15),
    // chunk = (lane>>4) ^ (((lane&15)>>1)&3)  (Rbase mult of 16 -> invariant)
    int rl = lane & 15, cq = lane >> 4;
    int roff = rl * 64 + ((cq ^ ((rl >> 1) & 3)) * 16);
    int aoff = wm * 8192 + roff;            // + m*1024 + AB(buf,ks)
    int boff = wn * 4096 + roff;            // + n*1024 + BB(buf,ks)

    // stage-side: slot s = p*512+tid -> r = s>>2, holds global chunk
    // gc = (s&3) ^ ((r>>1)&3)  (inverse of the read swizzle)
    const unsigned short* gA[2]; const unsigned short* gB[2]; int ldst[2];
    #pragma unroll
    for (int p = 0; p < 2; p++) {
        int s = p * 512 + tid;
        int r = s >> 2;
        int gc = (s & 3) ^ ((r >> 1) & 3);
        gA[p] = A + (rowBase + r) * (long)K + gc * 8;
        gB[p] = B + (colBase + r) * (long)K + gc * 8;
        ldst[p] = s * 16;
    }

    // prologue: tile0 fully (8 loads, FIRST in program order), then tile1 k0
    // halves (4 loads). vmcnt(4) -> tile0 landed, tile1.k0 stays in flight.
    #pragma unroll
    for (int p = 0; p < 2; p++) {
        STA(p, 0,  AB(0,0));
        STA(p, 32, AB(0,1));
        STB(p, 0,  BB(0,0));
        STB(p, 32, BB(0,1));
    }
    #pragma unroll
    for (int p = 0; p < 2; p++) {
        STA(p, 64, AB(1,0));
        STB(p, 64, BB(1,0));
    }
    VMC(4);
    __builtin_amdgcn_s_barrier();

    // main loop: tiles (2i, 2i+1); covers tiles 0..NT-3
    const int nit = (K >> 7) - 1;
    for (int i = 0; i < nit; i++) {
        PHASE(0,0,0, { STA(0,96,AB(1,1));  STA(1,96,AB(1,1));  }, );
        PHASE(0,0,4, { STB(0,96,BB(1,1));  STB(1,96,BB(1,1));  }, );
        PHASE(0,1,0, { STA(0,128,AB(0,0)); STA(1,128,AB(0,0)); }, );
        PHASE(0,1,4, { STB(0,128,BB(0,0)); STB(1,128,BB(0,0)); }, VMC(4); );
        PHASE(1,0,0, { STA(0,160,AB(0,1)); STA(1,160,AB(0,1)); }, );
        PHASE(1,0,4, { STB(0,160,BB(0,1)); STB(1,160,BB(0,1)); }, );
        PHASE(1,1,0, { STA(0,192,AB(1,0)); STA(1,192,AB(1,0)); }, );
        PHASE(1,1,4, { STB(0,192,BB(1,0)); STB(1,192,BB(1,0)); }, VMC(4); );
        gA[0] += 128; gA[1] += 128; gB[0] += 128; gB[1] += 128;
    }
    // tail tile NT-2 (buf0): stage last halves of NT-1, then full drain
    PHASE(0,0,0, { STA(0,96,AB(1,1)); STA(1,96,AB(1,1)); }, );
    PHASE(0,0,4, { STB(0,96,BB(1,1)); STB(1,96,BB(1,1)); }, );
    PHASE(0,1,0, { }, );
    PHASE(0,1,4, { }, VMC(0); );
    // tail tile NT-1 (buf1): pure compute
    PHASE(1,0,0, { }, );
    PHASE(1,0,4, { }, );
    PHASE(1,1,0, { }, );
    PHASE(1,1,4, { }, );

    float sA = fmaxf(__uint_as_float(*amaxA_bits) * (1.0f / 128.0f), 1e-12f);
    float sB = fmaxf(__uint_as_float(*amaxB_bits) * (1.0f / 127.0f), 1e-12f);
    float sAB = sA * sB;
    int cr = cq * 4;            // C row base within 16 (row=(lane>>4)*4+reg)
    int cc = rl;                // C col within 16     (col=lane&15)

    if (EPI == 0) {
        unsigned short* Hm = (unsigned short*)Cout;
        float mx = 0.f;
        #pragma unroll
        for (int n = 0; n < 4; n++) {
            long col = colBase + wn * 64 + n * 16 + cc;
            float bv = bias[col];
            #pragma unroll
            for (int m = 0; m < 8; m++) {
                long row0 = rowBase + wm * 128 + m * 16 + cr;
                #pragma unroll
                for (int r = 0; r < 4; r++) {
                    float v = acc[m][n][r] * sAB + bv;
                    float g = 0.5f * v * (1.0f + erff(v * 0.70710678118654752f));
                    mx = fmaxf(mx, fabsf(g));
                    Hm[(row0 + r) * (long)ldc + col] = f2bf_rn(g);
                }
            }
        }
        block_atomic_max<8>(mx, amax_out, red, tid);
    } else {
        float* O = (float*)Cout;
        #pragma unroll
        for (int n = 0; n < 4; n++) {
            long col = colBase + wn * 64 + n * 16 + cc;
            float bv = bias[col];
            #pragma unroll
            for (int m = 0; m < 8; m++) {
                long row0 = rowBase + wm * 128 + m * 16 + cr;
                #pragma unroll
                for (int r = 0; r < 4; r++)
                    O[(row0 + r) * (long)ldc + col] = acc[m][n][r] * sAB + bv;
            }
        }
    }
}

// ---------------------------------------------------------------------------
extern "C" void kernel_launch(void* const* d_in, const int* in_sizes, int n_in,
                              void* d_out, int out_size, void* d_ws, size_t ws_size,
                              hipStream_t stream) {
    const float* x     = (const float*)d_in[0];
    const float* gamma = (const float*)d_in[1];
    const float* beta  = (const float*)d_in[2];
    const float* W1    = (const float*)d_in[3];
    const float* b1    = (const float*)d_in[4];
    const float* W2    = (const float*)d_in[5];
    const float* b2    = (const float*)d_in[6];
    float* out = (float*)d_out;

    const int  D  = in_sizes[1];          // 768
    const int  H  = in_sizes[4];          // 3072
    const long NR = (long)in_sizes[0] / D;  // 65536

    char* ws = (char*)d_ws;
    unsigned* amax = (unsigned*)ws;                 // [0]=x [1]=W1 [2]=W2 [3]=h
    unsigned short* qx  = (unsigned short*)(ws + 256);
    unsigned short* qw1 = qx  + (size_t)NR * D;
    unsigned short* qw2 = qw1 + (size_t)H * D;
    unsigned short* hq  = qw2 + (size_t)H * D;      // NR*H bf16

    hipMemsetAsync(amax, 0, 16, stream);

    long wn4 = (long)H * D / 4;
    absmax_kernel<<<1024, 256, 0, stream>>>(W1, wn4, amax + 1);
    absmax_kernel<<<1024, 256, 0, stream>>>(W2, wn4, amax + 2);
    ln_absmax_kernel<<<2048, 256, 0, stream>>>(x, gamma, beta, amax + 0, NR);

    quant_w_kernel<<<(unsigned)((wn4 + 255) / 256), 256, 0, stream>>>(W1, qw1, wn4, amax + 1);
    quant_w_kernel<<<(unsigned)((wn4 + 255) / 256), 256, 0, stream>>>(W2, qw2, wn4, amax + 2);
    ln_quant_kernel<<<(unsigned)(NR / 4), 256, 0, stream>>>(x, gamma, beta, qx, amax + 0, NR);

    dim3 g1(H / 256, (unsigned)(NR / 256));   // 12 x 256 = 3072 wg (%8==0)
    gemm256<0><<<g1, 512, 0, stream>>>(qx, qw1, D, amax + 0, amax + 1, b1,
                                       (void*)hq, H, amax + 3);

    long n8 = NR * (long)H / 8;
    quant_h_kernel<<<(unsigned)((n8 + 255) / 256), 256, 0, stream>>>(hq, amax + 3, n8);

    dim3 g2(D / 256, (unsigned)(NR / 256));   // 3 x 256 = 768 wg (%8==0)
    gemm256<1><<<g2, 512, 0, stream>>>(hq, qw2, H, amax + 3, amax + 2, b2,
                                       (void*)out, D, nullptr);
}